// Round 8
// baseline (355.099 us; speedup 1.0000x reference)
//
#include <hip/hip_runtime.h>
#include <hip/hip_fp16.h>

// ---------------- degree / CSR build ----------------

__global__ void zero_ints(int* __restrict__ a, int* __restrict__ b, int n) {
    int i = blockIdx.x * blockDim.x + threadIdx.x;
    if (i < n) { a[i] = 0; b[i] = 0; }
}

__global__ void count_dst(const int* __restrict__ dst, int E, int* __restrict__ cnt) {
    int e = blockIdx.x * blockDim.x + threadIdx.x;
    if (e < E) atomicAdd(&cnt[dst[e]], 1);
}

__global__ void compute_dis(const int* __restrict__ cnt, float* __restrict__ dis, int n) {
    int i = blockIdx.x * blockDim.x + threadIdx.x;
    if (i < n) dis[i] = rsqrtf((float)(cnt[i] + 1));  // +1 self-loop
}

// block scans 1024 elements (256 thr x 4); writes local-exclusive scan + block total
__global__ __launch_bounds__(256) void scanA(const int* __restrict__ cnt,
                                             int* __restrict__ row_ptr,
                                             int* __restrict__ blockSums, int n) {
    __shared__ int s[256];
    int t = threadIdx.x;
    int base = blockIdx.x * 1024 + t * 4;
    int v0 = (base + 0 < n) ? cnt[base + 0] : 0;
    int v1 = (base + 1 < n) ? cnt[base + 1] : 0;
    int v2 = (base + 2 < n) ? cnt[base + 2] : 0;
    int v3 = (base + 3 < n) ? cnt[base + 3] : 0;
    int tsum = v0 + v1 + v2 + v3;
    s[t] = tsum;
    __syncthreads();
    for (int off = 1; off < 256; off <<= 1) {
        int u = (t >= off) ? s[t - off] : 0;
        __syncthreads();
        s[t] += u;
        __syncthreads();
    }
    int excl = s[t] - tsum;
    if (base + 0 < n) row_ptr[base + 0] = excl;
    if (base + 1 < n) row_ptr[base + 1] = excl + v0;
    if (base + 2 < n) row_ptr[base + 2] = excl + v0 + v1;
    if (base + 3 < n) row_ptr[base + 3] = excl + v0 + v1 + v2;
    if (t == 255) blockSums[blockIdx.x] = s[255];
}

// single wave scans <=64 block sums -> exclusive offsets
__global__ void scanB(const int* __restrict__ blockSums, int* __restrict__ blockOff, int B) {
    int t = threadIdx.x;  // 64 threads
    int v = (t < B) ? blockSums[t] : 0;
    int orig = v;
    for (int off = 1; off < 64; off <<= 1) {
        int u = __shfl_up(v, off, 64);
        if (t >= off) v += u;
    }
    if (t < B) blockOff[t] = v - orig;
}

__global__ __launch_bounds__(256) void scanC(int* __restrict__ row_ptr,
                                             const int* __restrict__ blockOff, int n, int E) {
    int base = blockIdx.x * 1024 + threadIdx.x * 4;
    int off = blockOff[blockIdx.x];
    #pragma unroll
    for (int j = 0; j < 4; ++j)
        if (base + j < n) row_ptr[base + j] += off;
    if (blockIdx.x == 0 && threadIdx.x == 0) row_ptr[n] = E;
}

// edges[slot] = packed { u16 src, fp16 coef }.
// 4 edges per thread via int4 loads -> 4 independent atomic chains (ILP).
__global__ __launch_bounds__(256) void fill_csr(const int* __restrict__ src,
                                                const int* __restrict__ dst, int E,
                                                const int* __restrict__ row_ptr,
                                                int* __restrict__ fillc,
                                                const float* __restrict__ dis,
                                                unsigned int* __restrict__ edges) {
    int i = blockIdx.x * blockDim.x + threadIdx.x;
    int e0 = i * 4;
    if (e0 + 3 < E) {
        int4 d4 = ((const int4*)dst)[i];
        int4 s4 = ((const int4*)src)[i];
        float dd0 = dis[d4.x], dd1 = dis[d4.y], dd2 = dis[d4.z], dd3 = dis[d4.w];
        float ds0 = dis[s4.x], ds1 = dis[s4.y], ds2 = dis[s4.z], ds3 = dis[s4.w];
        int o0 = atomicAdd(&fillc[d4.x], 1);
        int o1 = atomicAdd(&fillc[d4.y], 1);
        int o2 = atomicAdd(&fillc[d4.z], 1);
        int o3 = atomicAdd(&fillc[d4.w], 1);
        edges[row_ptr[d4.x] + o0] = (unsigned)s4.x |
            ((unsigned)__half_as_ushort(__float2half_rn(ds0 * dd0)) << 16);
        edges[row_ptr[d4.y] + o1] = (unsigned)s4.y |
            ((unsigned)__half_as_ushort(__float2half_rn(ds1 * dd1)) << 16);
        edges[row_ptr[d4.z] + o2] = (unsigned)s4.z |
            ((unsigned)__half_as_ushort(__float2half_rn(ds2 * dd2)) << 16);
        edges[row_ptr[d4.w] + o3] = (unsigned)s4.w |
            ((unsigned)__half_as_ushort(__float2half_rn(ds3 * dd3)) << 16);
    } else {
        for (int e = e0; e < E; ++e) {
            int d = dst[e], s = src[e];
            int ofs = atomicAdd(&fillc[d], 1);
            edges[row_ptr[d] + ofs] = (unsigned)s |
                ((unsigned)__half_as_ushort(__float2half_rn(dis[s] * dis[d])) << 16);
        }
    }
}

__device__ __forceinline__ void unpack_edge(unsigned int w, int& s, float& c) {
    s = (int)(w & 0xffffu);
    c = __half2float(__ushort_as_half((unsigned short)(w >> 16)));
}

// ---------------- GEMM: Y[M,N](fp16) = X[M,128](f32) @ W[128,N](f32) ----------------

template <int N>
__global__ __launch_bounds__(256) void gemm_k128(const float* __restrict__ X,
                                                 const float* __restrict__ W,
                                                 __half* __restrict__ Y, int M) {
    constexpr int CG = N / 4;
    constexpr int RG = 256 / CG;
    constexpr int RPT = 64 / RG;
    __shared__ float Xs[64 * 128];    // 32 KB
    int t = threadIdx.x;
    int m0 = blockIdx.x * 64;
    for (int j = t * 4; j < 64 * 128; j += 1024) {
        int row = m0 + (j >> 7);
        float4 v = (row < M) ? *(const float4*)&X[(size_t)row * 128 + (j & 127)]
                             : float4{0.f, 0.f, 0.f, 0.f};
        *(float4*)&Xs[j] = v;
    }
    __syncthreads();
    int mc = t % CG;
    int mr = t / CG;
    float acc[RPT][4] = {};
    const float* xbase = &Xs[(mr * RPT) * 128];
    const float* wp = W + mc * 4;
    #pragma unroll 4
    for (int k = 0; k < 128; ++k) {
        float4 w = *(const float4*)&wp[k * N];
        #pragma unroll
        for (int r = 0; r < RPT; ++r) {
            float xv = xbase[r * 128 + k];
            acc[r][0] += xv * w.x;
            acc[r][1] += xv * w.y;
            acc[r][2] += xv * w.z;
            acc[r][3] += xv * w.w;
        }
    }
    #pragma unroll
    for (int r = 0; r < RPT; ++r) {
        int row = m0 + mr * RPT + r;
        if (row < M) {
            union { __half2 h[2]; float2 f; } u;
            u.h[0] = __floats2half2_rn(acc[r][0], acc[r][1]);
            u.h[1] = __floats2half2_rn(acc[r][2], acc[r][3]);
            *(float2*)&Y[(size_t)row * N + mc * 4] = u.f;
        }
    }
}

// ---------------- sliced aggregation D=128 ----------------
// h fp16 [n][128] row-major. 4 slices of 32 dims (64B line each).
// slot = blockIdx&7 -> XCD under round-robin; slice = slot>>1 (2 XCDs/slice,
// per-XCD h working set = 3.2MB -> L2-resident); slot&1 = node-group bit so
// each (node,slice) is covered exactly once independent of the XCD mapping.
// 16-lane group per node: gather = exactly one 64B line per edge.

__global__ __launch_bounds__(256) void agg_sl128(const __half2* __restrict__ hp,
                                                 const int* __restrict__ row_ptr,
                                                 const unsigned int* __restrict__ edges,
                                                 const float* __restrict__ dis,
                                                 const float* __restrict__ bias,
                                                 float* __restrict__ out, int n) {
    int slot = blockIdx.x & 7;
    int grp = blockIdx.x >> 3;
    int slice = slot >> 1;
    int t = threadIdx.x;
    int node = grp * 32 + (slot & 1) * 16 + (t >> 4);
    if (node >= n) return;
    int sub = t & 15;
    const __half2* hbase = hp + slice * 16 + sub;
    int beg = row_ptr[node], end = row_ptr[node + 1];
    float di = dis[node];
    float cs = di * di;
    float2 sv = __half22float2(hbase[(size_t)node * 64]);
    float2 a0 = {cs * sv.x, cs * sv.y};
    float2 a1 = {0.f, 0.f};
    int e = beg;
    for (; e + 2 <= end; e += 2) {
        unsigned int w0 = edges[e], w1 = edges[e + 1];
        int s0, s1; float c0, c1;
        unpack_edge(w0, s0, c0); unpack_edge(w1, s1, c1);
        float2 u0 = __half22float2(hbase[(size_t)s0 * 64]);
        float2 u1 = __half22float2(hbase[(size_t)s1 * 64]);
        a0.x += c0 * u0.x; a0.y += c0 * u0.y;
        a1.x += c1 * u1.x; a1.y += c1 * u1.y;
    }
    if (e < end) {
        int s0; float c0;
        unpack_edge(edges[e], s0, c0);
        float2 u0 = __half22float2(hbase[(size_t)s0 * 64]);
        a0.x += c0 * u0.x; a0.y += c0 * u0.y;
    }
    float2 bv = *(const float2*)&bias[slice * 32 + sub * 2];
    float2 o;
    o.x = fmaxf(a0.x + a1.x + bv.x, 0.f);
    o.y = fmaxf(a0.y + a1.y + bv.y, 0.f);
    *(float2*)&out[(size_t)node * 128 + slice * 32 + sub * 2] = o;
}

// ---------------- aggregation D=64: 2 nodes per wave (32 lanes x half2) ----------------

__global__ __launch_bounds__(256) void agg_gcn64(const __half2* __restrict__ hp,
                                                 const int* __restrict__ row_ptr,
                                                 const unsigned int* __restrict__ edges,
                                                 const float* __restrict__ dis,
                                                 const float* __restrict__ bias,
                                                 float* __restrict__ out, int n) {
    int node = (blockIdx.x * 256 + threadIdx.x) >> 5;
    if (node >= n) return;
    int l = threadIdx.x & 31;
    int beg = row_ptr[node], end = row_ptr[node + 1];
    float di = dis[node];
    float cs = di * di;
    float2 sv = __half22float2(hp[(size_t)node * 32 + l]);
    float2 a0 = {cs * sv.x, cs * sv.y};
    float2 a1 = {0.f, 0.f};
    int e = beg;
    for (; e + 2 <= end; e += 2) {
        unsigned int w0 = edges[e], w1 = edges[e + 1];
        int s0, s1; float c0, c1;
        unpack_edge(w0, s0, c0); unpack_edge(w1, s1, c1);
        float2 u0 = __half22float2(hp[(size_t)s0 * 32 + l]);
        float2 u1 = __half22float2(hp[(size_t)s1 * 32 + l]);
        a0.x += c0 * u0.x; a0.y += c0 * u0.y;
        a1.x += c1 * u1.x; a1.y += c1 * u1.y;
    }
    if (e < end) {
        int s0; float c0;
        unpack_edge(edges[e], s0, c0);
        float2 u0 = __half22float2(hp[(size_t)s0 * 32 + l]);
        a0.x += c0 * u0.x; a0.y += c0 * u0.y;
    }
    float2 bv = ((const float2*)bias)[l];
    float2 o;
    o.x = fmaxf(a0.x + a1.x + bv.x, 0.f);
    o.y = fmaxf(a0.y + a1.y + bv.y, 0.f);
    ((float2*)out)[(size_t)node * 32 + l] = o;
}

// ---------------- projection + relu + row-normalize: register-blocked GEMM ----------------

__global__ __launch_bounds__(256) void proj_norm2(const float* __restrict__ O,
                                                  const float* __restrict__ Wp,
                                                  float* __restrict__ P, int n) {
    __shared__ float oT[64 * 68];  // [k][node], stride 68 keeps float4 16B-aligned
    __shared__ float Ws[64 * 64];  // [k][col]
    int t = threadIdx.x;
    int base = blockIdx.x * 64;
    for (int j = t * 4; j < 4096; j += 1024)
        *(float4*)&Ws[j] = *(const float4*)&Wp[j];
    for (int j = t * 4; j < 4096; j += 1024) {
        int row = j >> 6;   // node-in-block
        int col = j & 63;   // k
        int node = base + row;
        float4 v = (node < n) ? *(const float4*)&O[(size_t)node * 64 + col]
                              : float4{0.f, 0.f, 0.f, 0.f};
        oT[(col + 0) * 68 + row] = v.x;
        oT[(col + 1) * 68 + row] = v.y;
        oT[(col + 2) * 68 + row] = v.z;
        oT[(col + 3) * 68 + row] = v.w;
    }
    __syncthreads();
    int cg = t & 15;   // col group (4 cols)
    int ng = t >> 4;   // node group (4 nodes)
    float acc[4][4] = {};
    const float* otp = &oT[ng * 4];
    const float* wsp = &Ws[cg * 4];
    #pragma unroll 2
    for (int k = 0; k < 64; ++k) {
        float4 ov = *(const float4*)&otp[k * 68];
        float4 wv = *(const float4*)&wsp[k * 64];
        #pragma unroll
        for (int i = 0; i < 4; ++i) {
            float o = (&ov.x)[i];
            acc[i][0] += o * wv.x;
            acc[i][1] += o * wv.y;
            acc[i][2] += o * wv.z;
            acc[i][3] += o * wv.w;
        }
    }
    #pragma unroll
    for (int i = 0; i < 4; ++i) {
        float4 p;
        p.x = fmaxf(acc[i][0], 0.f);
        p.y = fmaxf(acc[i][1], 0.f);
        p.z = fmaxf(acc[i][2], 0.f);
        p.w = fmaxf(acc[i][3], 0.f);
        float ss = p.x * p.x + p.y * p.y + p.z * p.z + p.w * p.w;
        #pragma unroll
        for (int off = 1; off < 16; off <<= 1) ss += __shfl_xor(ss, off, 64);
        float norm = sqrtf(ss);
        float sc = 1.0f / fmaxf(norm, 1e-12f);
        int node = base + ng * 4 + i;
        if (node < n) {
            p.x *= sc; p.y *= sc; p.z *= sc; p.w *= sc;
            *(float4*)&P[(size_t)node * 64 + cg * 4] = p;
        }
    }
}

// ---------------- launch ----------------

static inline size_t ws_align(size_t x) { return (x + 255) & ~(size_t)255; }

extern "C" void kernel_launch(void* const* d_in, const int* in_sizes, int n_in,
                              void* d_out, int out_size, void* d_ws, size_t ws_size,
                              hipStream_t stream) {
    const float* x  = (const float*)d_in[0];
    const int*   ei = (const int*)d_in[1];
    const float* W1 = (const float*)d_in[2];
    const float* b1 = (const float*)d_in[3];
    const float* W2 = (const float*)d_in[4];
    const float* b2 = (const float*)d_in[5];
    const float* W3 = (const float*)d_in[6];
    const float* b3 = (const float*)d_in[7];
    const float* Wp = (const float*)d_in[8];

    int n = in_sizes[0] / 128;
    int E = in_sizes[1] / 2;
    const int* src = ei;
    const int* dst = ei + E;

    char* ws = (char*)d_ws;
    size_t off = 0;
    auto alloc = [&](size_t bytes) -> void* {
        void* p = ws + off;
        off = ws_align(off + bytes);
        return p;
    };
    __half* bufH    = (__half*)alloc((size_t)n * 128 * 2);  // fp16 GEMM out (gather operand)
    float*  bufF    = (float*)alloc((size_t)n * 128 * 4);   // f32 agg out (GEMM input)
    int*   cnt      = (int*)alloc((size_t)n * 4);
    int*   fillc    = (int*)alloc((size_t)n * 4);
    float* dis      = (float*)alloc((size_t)n * 4);
    int*   row_ptr  = (int*)alloc((size_t)(n + 1) * 4);
    unsigned int* edges = (unsigned int*)alloc((size_t)E * 4);
    int*   blockSums = (int*)alloc(256);
    int*   blockOff  = (int*)alloc(256);
    (void)off; (void)ws_size;

    int B = (n + 1023) / 1024;
    zero_ints<<<(n + 255) / 256, 256, 0, stream>>>(cnt, fillc, n);
    count_dst<<<(E + 255) / 256, 256, 0, stream>>>(dst, E, cnt);
    compute_dis<<<(n + 255) / 256, 256, 0, stream>>>(cnt, dis, n);
    scanA<<<B, 256, 0, stream>>>(cnt, row_ptr, blockSums, n);
    scanB<<<1, 64, 0, stream>>>(blockSums, blockOff, B);
    scanC<<<B, 256, 0, stream>>>(row_ptr, blockOff, n, E);
    int fthreads = (E + 3) / 4;
    fill_csr<<<(fthreads + 255) / 256, 256, 0, stream>>>(src, dst, E, row_ptr, fillc, dis, edges);

    int gblocks = (n + 63) / 64;
    int slblocks = ((n + 31) / 32) * 8;  // (node,slice) pairs
    int a64blocks = (n + 7) / 8;         // 2 nodes/wave (8 nodes/block)
    int pblocks = (n + 63) / 64;
    float* outp = (float*)d_out;

    gemm_k128<128><<<gblocks, 256, 0, stream>>>(x, W1, bufH, n);
    agg_sl128<<<slblocks, 256, 0, stream>>>((const __half2*)bufH, row_ptr, edges, dis, b1, bufF, n);
    gemm_k128<128><<<gblocks, 256, 0, stream>>>(bufF, W2, bufH, n);
    agg_sl128<<<slblocks, 256, 0, stream>>>((const __half2*)bufH, row_ptr, edges, dis, b2, bufF, n);
    gemm_k128<64><<<gblocks, 256, 0, stream>>>(bufF, W3, bufH, n);
    agg_gcn64<<<a64blocks, 256, 0, stream>>>((const __half2*)bufH, row_ptr, edges, dis, b3, bufF, n);
    proj_norm2<<<pblocks, 256, 0, stream>>>(bufF, Wp, outp, n);
}

// Round 9
// 287.429 us; speedup vs baseline: 1.2354x; 1.2354x over previous
//
#include <hip/hip_runtime.h>
#include <hip/hip_fp16.h>

typedef _Float16 half8v __attribute__((ext_vector_type(8)));
typedef _Float16 half4v __attribute__((ext_vector_type(4)));
typedef float f32x4 __attribute__((ext_vector_type(4)));

// ---------------- degree / CSR build ----------------

__global__ void zero_cnt(int* __restrict__ a, int n) {
    int i = blockIdx.x * blockDim.x + threadIdx.x;
    if (i < n) a[i] = 0;
}

__global__ void count_dst(const int* __restrict__ dst, int E, int* __restrict__ cnt) {
    int e = blockIdx.x * blockDim.x + threadIdx.x;
    if (e < E) atomicAdd(&cnt[dst[e]], 1);
}

__global__ void compute_dis(const int* __restrict__ cnt, float* __restrict__ dis, int n) {
    int i = blockIdx.x * blockDim.x + threadIdx.x;
    if (i < n) dis[i] = rsqrtf((float)(cnt[i] + 1));  // +1 self-loop
}

__global__ __launch_bounds__(256) void scanA(const int* __restrict__ cnt,
                                             int* __restrict__ row_ptr,
                                             int* __restrict__ blockSums, int n) {
    __shared__ int s[256];
    int t = threadIdx.x;
    int base = blockIdx.x * 1024 + t * 4;
    int v0 = (base + 0 < n) ? cnt[base + 0] : 0;
    int v1 = (base + 1 < n) ? cnt[base + 1] : 0;
    int v2 = (base + 2 < n) ? cnt[base + 2] : 0;
    int v3 = (base + 3 < n) ? cnt[base + 3] : 0;
    int tsum = v0 + v1 + v2 + v3;
    s[t] = tsum;
    __syncthreads();
    for (int off = 1; off < 256; off <<= 1) {
        int u = (t >= off) ? s[t - off] : 0;
        __syncthreads();
        s[t] += u;
        __syncthreads();
    }
    int excl = s[t] - tsum;
    if (base + 0 < n) row_ptr[base + 0] = excl;
    if (base + 1 < n) row_ptr[base + 1] = excl + v0;
    if (base + 2 < n) row_ptr[base + 2] = excl + v0 + v1;
    if (base + 3 < n) row_ptr[base + 3] = excl + v0 + v1 + v2;
    if (t == 255) blockSums[blockIdx.x] = s[255];
}

__global__ void scanB(const int* __restrict__ blockSums, int* __restrict__ blockOff, int B) {
    int t = threadIdx.x;  // 64 threads
    int v = (t < B) ? blockSums[t] : 0;
    int orig = v;
    for (int off = 1; off < 64; off <<= 1) {
        int u = __shfl_up(v, off, 64);
        if (t >= off) v += u;
    }
    if (t < B) blockOff[t] = v - orig;
}

// adds block offsets AND initializes fillc = row start (removes row_ptr load from fill chain)
__global__ __launch_bounds__(256) void scanC(int* __restrict__ row_ptr,
                                             int* __restrict__ fillc,
                                             const int* __restrict__ blockOff, int n, int E) {
    int base = blockIdx.x * 1024 + threadIdx.x * 4;
    int off = blockOff[blockIdx.x];
    #pragma unroll
    for (int j = 0; j < 4; ++j)
        if (base + j < n) {
            int v = row_ptr[base + j] + off;
            row_ptr[base + j] = v;
            fillc[base + j] = v;
        }
    if (blockIdx.x == 0 && threadIdx.x == 0) row_ptr[n] = E;
}

// edges[slot] = packed { u16 src, fp16 coef }; fillc holds running slot directly
__global__ void fill_csr(const int* __restrict__ src, const int* __restrict__ dst, int E,
                         int* __restrict__ fillc, const float* __restrict__ dis,
                         unsigned int* __restrict__ edges) {
    int e = blockIdx.x * blockDim.x + threadIdx.x;
    if (e >= E) return;
    int d = dst[e], s = src[e];
    float coef = dis[s] * dis[d];
    int slot = atomicAdd(&fillc[d], 1);
    edges[slot] = (unsigned)s |
                  ((unsigned)__half_as_ushort(__float2half_rn(coef)) << 16);
}

__device__ __forceinline__ void unpack_edge(unsigned int w, int& s, float& c) {
    s = (int)(w & 0xffffu);
    c = __half2float(__ushort_as_half((unsigned short)(w >> 16)));
}

// ---------------- conversions ----------------

__global__ void cvt_x(const float* __restrict__ x, _Float16* __restrict__ xh, int total4) {
    int i = blockIdx.x * blockDim.x + threadIdx.x;  // over total/4
    if (i >= total4) return;
    float4 v = ((const float4*)x)[i];
    half4v hv = {(_Float16)v.x, (_Float16)v.y, (_Float16)v.z, (_Float16)v.w};
    *(half4v*)&xh[i * 4] = hv;
}

// Wt[n][k] = W[k][n], fp16
__global__ void cvt_w(const float* __restrict__ W, _Float16* __restrict__ Wt, int K, int N) {
    int i = blockIdx.x * blockDim.x + threadIdx.x;
    if (i >= N * K) return;
    int nn = i >> 7, kk = i & 127;  // K == 128 always
    Wt[i] = (_Float16)W[kk * N + nn];
}

// ---------------- MFMA GEMM: Y[M,N](fp16) = X[M,128](fp16) @ W(fp16, pre-transposed Wt[N][128]) ----------------
// block = 256 thr = 4 waves; wave computes 16 rows x N cols; mfma_f32_16x16x32_f16.
// A frag: row = lane&15, k = (lane>>4)*8+j (contiguous half8). B frag: col = lane&15 (row of Wt),
// same k layout -> contiguous half8 from Wt. D: col = lane&15, row = (lane>>4)*4+reg.

template <int N>
__global__ __launch_bounds__(256) void gemm_mfma(const _Float16* __restrict__ Xh,
                                                 const _Float16* __restrict__ Wt,
                                                 _Float16* __restrict__ Y, int M) {
    constexpr int NT = N / 16;
    int wave = threadIdx.x >> 6;
    int lane = threadIdx.x & 63;
    int m0 = blockIdx.x * 64 + wave * 16;
    int r = lane & 15;
    int kb = lane >> 4;
    int ar = m0 + r; if (ar >= M) ar = M - 1;  // clamp (A row m only affects D row m)
    const _Float16* arow = Xh + (size_t)ar * 128 + kb * 8;
    f32x4 acc[NT] = {};
    #pragma unroll
    for (int kk = 0; kk < 128; kk += 32) {
        half8v a = *(const half8v*)(arow + kk);
        #pragma unroll
        for (int c = 0; c < NT; ++c) {
            half8v b = *(const half8v*)(Wt + (size_t)(c * 16 + r) * 128 + kk + kb * 8);
            acc[c] = __builtin_amdgcn_mfma_f32_16x16x32_f16(a, b, acc[c], 0, 0, 0);
        }
    }
    #pragma unroll
    for (int j = 0; j < 4; ++j) {
        int row = m0 + kb * 4 + j;
        if (row < M) {
            #pragma unroll
            for (int c = 0; c < NT; ++c)
                Y[(size_t)row * N + c * 16 + r] = (_Float16)acc[c][j];
        }
    }
}

// ---------------- aggregation D=128: wave per node, lane = half2(2 dims), fp16 in/out ----------------

__global__ __launch_bounds__(256) void agg_gcn128(const __half2* __restrict__ hp,
                                                  const int* __restrict__ row_ptr,
                                                  const unsigned int* __restrict__ edges,
                                                  const float* __restrict__ dis,
                                                  const float* __restrict__ bias,
                                                  __half2* __restrict__ out, int n) {
    int wid = (blockIdx.x * 256 + threadIdx.x) >> 6;
    if (wid >= n) return;
    int lane = threadIdx.x & 63;
    int beg = row_ptr[wid], end = row_ptr[wid + 1];
    float di = dis[wid];
    float cs = di * di;
    float2 sv = __half22float2(hp[(size_t)wid * 64 + lane]);
    float2 a0 = {cs * sv.x, cs * sv.y};
    float2 a1 = {0.f, 0.f}, a2 = {0.f, 0.f}, a3 = {0.f, 0.f};
    int e = beg;
    for (; e + 4 <= end; e += 4) {
        unsigned int w0 = edges[e], w1 = edges[e + 1], w2 = edges[e + 2], w3 = edges[e + 3];
        int s0, s1, s2, s3; float c0, c1, c2, c3;
        unpack_edge(w0, s0, c0); unpack_edge(w1, s1, c1);
        unpack_edge(w2, s2, c2); unpack_edge(w3, s3, c3);
        float2 u0 = __half22float2(hp[(size_t)s0 * 64 + lane]);
        float2 u1 = __half22float2(hp[(size_t)s1 * 64 + lane]);
        float2 u2 = __half22float2(hp[(size_t)s2 * 64 + lane]);
        float2 u3 = __half22float2(hp[(size_t)s3 * 64 + lane]);
        a0.x += c0 * u0.x; a0.y += c0 * u0.y;
        a1.x += c1 * u1.x; a1.y += c1 * u1.y;
        a2.x += c2 * u2.x; a2.y += c2 * u2.y;
        a3.x += c3 * u3.x; a3.y += c3 * u3.y;
    }
    for (; e < end; ++e) {
        int s0; float c0;
        unpack_edge(edges[e], s0, c0);
        float2 u0 = __half22float2(hp[(size_t)s0 * 64 + lane]);
        a0.x += c0 * u0.x; a0.y += c0 * u0.y;
    }
    float2 bv = ((const float2*)bias)[lane];
    float ox = fmaxf(a0.x + a1.x + a2.x + a3.x + bv.x, 0.f);
    float oy = fmaxf(a0.y + a1.y + a2.y + a3.y + bv.y, 0.f);
    out[(size_t)wid * 64 + lane] = __floats2half2_rn(ox, oy);
}

// ---------------- aggregation D=64: 2 nodes per wave (32 lanes x half2), fp16 in/out ----------------

__global__ __launch_bounds__(256) void agg_gcn64(const __half2* __restrict__ hp,
                                                 const int* __restrict__ row_ptr,
                                                 const unsigned int* __restrict__ edges,
                                                 const float* __restrict__ dis,
                                                 const float* __restrict__ bias,
                                                 __half2* __restrict__ out, int n) {
    int node = (blockIdx.x * 256 + threadIdx.x) >> 5;
    if (node >= n) return;
    int l = threadIdx.x & 31;
    int beg = row_ptr[node], end = row_ptr[node + 1];
    float di = dis[node];
    float cs = di * di;
    float2 sv = __half22float2(hp[(size_t)node * 32 + l]);
    float2 a0 = {cs * sv.x, cs * sv.y};
    float2 a1 = {0.f, 0.f};
    int e = beg;
    for (; e + 2 <= end; e += 2) {
        unsigned int w0 = edges[e], w1 = edges[e + 1];
        int s0, s1; float c0, c1;
        unpack_edge(w0, s0, c0); unpack_edge(w1, s1, c1);
        float2 u0 = __half22float2(hp[(size_t)s0 * 32 + l]);
        float2 u1 = __half22float2(hp[(size_t)s1 * 32 + l]);
        a0.x += c0 * u0.x; a0.y += c0 * u0.y;
        a1.x += c1 * u1.x; a1.y += c1 * u1.y;
    }
    if (e < end) {
        int s0; float c0;
        unpack_edge(edges[e], s0, c0);
        float2 u0 = __half22float2(hp[(size_t)s0 * 32 + l]);
        a0.x += c0 * u0.x; a0.y += c0 * u0.y;
    }
    float2 bv = ((const float2*)bias)[l];
    float ox = fmaxf(a0.x + a1.x + bv.x, 0.f);
    float oy = fmaxf(a0.y + a1.y + bv.y, 0.f);
    out[(size_t)node * 32 + l] = __floats2half2_rn(ox, oy);
}

// ---------------- projection + relu + row-normalize (fp16 input, f32 output) ----------------

__global__ __launch_bounds__(256) void proj_norm2(const _Float16* __restrict__ O,
                                                  const float* __restrict__ Wp,
                                                  float* __restrict__ P, int n) {
    __shared__ float oT[64 * 68];  // [k][node], stride 68 keeps float4 16B-aligned
    __shared__ float Ws[64 * 64];  // [k][col]
    int t = threadIdx.x;
    int base = blockIdx.x * 64;
    for (int j = t * 4; j < 4096; j += 1024)
        *(float4*)&Ws[j] = *(const float4*)&Wp[j];
    for (int j = t * 4; j < 4096; j += 1024) {
        int row = j >> 6;   // node-in-block
        int col = j & 63;   // k
        int node = base + row;
        half4v hv = (node < n) ? *(const half4v*)&O[(size_t)node * 64 + col]
                               : (half4v){(_Float16)0, (_Float16)0, (_Float16)0, (_Float16)0};
        oT[(col + 0) * 68 + row] = (float)hv[0];
        oT[(col + 1) * 68 + row] = (float)hv[1];
        oT[(col + 2) * 68 + row] = (float)hv[2];
        oT[(col + 3) * 68 + row] = (float)hv[3];
    }
    __syncthreads();
    int cg = t & 15;   // col group (4 cols)
    int ng = t >> 4;   // node group (4 nodes)
    float acc[4][4] = {};
    const float* otp = &oT[ng * 4];
    const float* wsp = &Ws[cg * 4];
    #pragma unroll 2
    for (int k = 0; k < 64; ++k) {
        float4 ov = *(const float4*)&otp[k * 68];
        float4 wv = *(const float4*)&wsp[k * 64];
        #pragma unroll
        for (int i = 0; i < 4; ++i) {
            float o = (&ov.x)[i];
            acc[i][0] += o * wv.x;
            acc[i][1] += o * wv.y;
            acc[i][2] += o * wv.z;
            acc[i][3] += o * wv.w;
        }
    }
    #pragma unroll
    for (int i = 0; i < 4; ++i) {
        float4 p;
        p.x = fmaxf(acc[i][0], 0.f);
        p.y = fmaxf(acc[i][1], 0.f);
        p.z = fmaxf(acc[i][2], 0.f);
        p.w = fmaxf(acc[i][3], 0.f);
        float ss = p.x * p.x + p.y * p.y + p.z * p.z + p.w * p.w;
        #pragma unroll
        for (int off = 1; off < 16; off <<= 1) ss += __shfl_xor(ss, off, 64);
        float norm = sqrtf(ss);
        float sc = 1.0f / fmaxf(norm, 1e-12f);
        int node = base + ng * 4 + i;
        if (node < n) {
            p.x *= sc; p.y *= sc; p.z *= sc; p.w *= sc;
            *(float4*)&P[(size_t)node * 64 + cg * 4] = p;
        }
    }
}

// ---------------- launch ----------------

static inline size_t ws_align(size_t x) { return (x + 255) & ~(size_t)255; }

extern "C" void kernel_launch(void* const* d_in, const int* in_sizes, int n_in,
                              void* d_out, int out_size, void* d_ws, size_t ws_size,
                              hipStream_t stream) {
    const float* x  = (const float*)d_in[0];
    const int*   ei = (const int*)d_in[1];
    const float* W1 = (const float*)d_in[2];
    const float* b1 = (const float*)d_in[3];
    const float* W2 = (const float*)d_in[4];
    const float* b2 = (const float*)d_in[5];
    const float* W3 = (const float*)d_in[6];
    const float* b3 = (const float*)d_in[7];
    const float* Wp = (const float*)d_in[8];

    int n = in_sizes[0] / 128;
    int E = in_sizes[1] / 2;
    const int* src = ei;
    const int* dst = ei + E;

    char* ws = (char*)d_ws;
    size_t off = 0;
    auto alloc = [&](size_t bytes) -> void* {
        void* p = ws + off;
        off = ws_align(off + bytes);
        return p;
    };
    _Float16* xh   = (_Float16*)alloc((size_t)n * 128 * 2);
    _Float16* bufA = (_Float16*)alloc((size_t)n * 128 * 2);  // gemm out / agg in
    _Float16* bufB = (_Float16*)alloc((size_t)n * 128 * 2);  // agg out / gemm in
    _Float16* Wt1  = (_Float16*)alloc(128 * 128 * 2);
    _Float16* Wt2  = (_Float16*)alloc(128 * 128 * 2);
    _Float16* Wt3  = (_Float16*)alloc(64 * 128 * 2);
    int*   cnt      = (int*)alloc((size_t)n * 4);
    int*   fillc    = (int*)alloc((size_t)n * 4);
    float* dis      = (float*)alloc((size_t)n * 4);
    int*   row_ptr  = (int*)alloc((size_t)(n + 1) * 4);
    unsigned int* edges = (unsigned int*)alloc((size_t)E * 4);
    int*   blockSums = (int*)alloc(256);
    int*   blockOff  = (int*)alloc(256);
    (void)off; (void)ws_size;

    int B = (n + 1023) / 1024;
    zero_cnt<<<(n + 255) / 256, 256, 0, stream>>>(cnt, n);
    count_dst<<<(E + 255) / 256, 256, 0, stream>>>(dst, E, cnt);
    compute_dis<<<(n + 255) / 256, 256, 0, stream>>>(cnt, dis, n);
    scanA<<<B, 256, 0, stream>>>(cnt, row_ptr, blockSums, n);
    scanB<<<1, 64, 0, stream>>>(blockSums, blockOff, B);
    scanC<<<B, 256, 0, stream>>>(row_ptr, fillc, blockOff, n, E);
    fill_csr<<<(E + 255) / 256, 256, 0, stream>>>(src, dst, E, fillc, dis, edges);

    int total4 = n * 128 / 4;
    cvt_x<<<(total4 + 255) / 256, 256, 0, stream>>>(x, xh, total4);
    cvt_w<<<(128 * 128 + 255) / 256, 256, 0, stream>>>(W1, Wt1, 128, 128);
    cvt_w<<<(128 * 128 + 255) / 256, 256, 0, stream>>>(W2, Wt2, 128, 128);
    cvt_w<<<(64 * 128 + 255) / 256, 256, 0, stream>>>(W3, Wt3, 128, 64);

    int gblocks = (n + 63) / 64;
    int ablocks = (n + 3) / 4;
    int a64blocks = (n + 7) / 8;
    int pblocks = (n + 63) / 64;
    float* outp = (float*)d_out;

    gemm_mfma<128><<<gblocks, 256, 0, stream>>>(xh, Wt1, bufA, n);
    agg_gcn128<<<ablocks, 256, 0, stream>>>((const __half2*)bufA, row_ptr, edges, dis, b1,
                                            (__half2*)bufB, n);
    gemm_mfma<128><<<gblocks, 256, 0, stream>>>(bufB, Wt2, bufA, n);
    agg_gcn128<<<ablocks, 256, 0, stream>>>((const __half2*)bufA, row_ptr, edges, dis, b2,
                                            (__half2*)bufB, n);
    gemm_mfma<64><<<gblocks, 256, 0, stream>>>(bufB, Wt3, bufA, n);
    agg_gcn64<<<a64blocks, 256, 0, stream>>>((const __half2*)bufA, row_ptr, edges, dis, b3,
                                             (__half2*)bufB, n);
    proj_norm2<<<pblocks, 256, 0, stream>>>(bufB, Wp, outp, n);
}

// Round 10
// 247.681 us; speedup vs baseline: 1.4337x; 1.1605x over previous
//
#include <hip/hip_runtime.h>
#include <hip/hip_fp16.h>

typedef _Float16 half8v __attribute__((ext_vector_type(8)));
typedef _Float16 half4v __attribute__((ext_vector_type(4)));
typedef float f32x4 __attribute__((ext_vector_type(4)));

// ---------------- fused: transpose-convert W1/W2/W3 to fp16 Wt[N][128] + zero cnt ----------------

__global__ void cvt_wz(const float* __restrict__ W1, const float* __restrict__ W2,
                       const float* __restrict__ W3,
                       _Float16* __restrict__ Wt1, _Float16* __restrict__ Wt2,
                       _Float16* __restrict__ Wt3,
                       int* __restrict__ cnt, int n) {
    int i = blockIdx.x * blockDim.x + threadIdx.x;
    if (i < 16384) {
        int nn = i >> 7, kk = i & 127;
        Wt1[i] = (_Float16)W1[kk * 128 + nn];
    } else if (i < 32768) {
        int j = i - 16384; int nn = j >> 7, kk = j & 127;
        Wt2[j] = (_Float16)W2[kk * 128 + nn];
    } else if (i < 40960) {
        int j = i - 32768; int nn = j >> 7, kk = j & 127;
        Wt3[j] = (_Float16)W3[kk * 64 + nn];
    }
    int z = i - 40960;
    if (z >= 0 && z < n) cnt[z] = 0;
}

// ---------------- degree count; atomic's return value IS the edge's rank in its row ----------------

__global__ void count_rank(const int* __restrict__ dst, int E, int* __restrict__ cnt,
                           unsigned short* __restrict__ rank) {
    int e = blockIdx.x * blockDim.x + threadIdx.x;
    if (e < E) rank[e] = (unsigned short)atomicAdd(&cnt[dst[e]], 1);
}

// scanA: block-local exclusive scan of cnt (1024 elems/block) + dis = rsqrt(deg+1)
__global__ __launch_bounds__(256) void scanA(const int* __restrict__ cnt,
                                             int* __restrict__ row_ptr,
                                             int* __restrict__ blockSums,
                                             float* __restrict__ dis, int n) {
    __shared__ int s[256];
    int t = threadIdx.x;
    int base = blockIdx.x * 1024 + t * 4;
    int v0 = (base + 0 < n) ? cnt[base + 0] : 0;
    int v1 = (base + 1 < n) ? cnt[base + 1] : 0;
    int v2 = (base + 2 < n) ? cnt[base + 2] : 0;
    int v3 = (base + 3 < n) ? cnt[base + 3] : 0;
    if (base + 0 < n) dis[base + 0] = rsqrtf((float)(v0 + 1));
    if (base + 1 < n) dis[base + 1] = rsqrtf((float)(v1 + 1));
    if (base + 2 < n) dis[base + 2] = rsqrtf((float)(v2 + 1));
    if (base + 3 < n) dis[base + 3] = rsqrtf((float)(v3 + 1));
    int tsum = v0 + v1 + v2 + v3;
    s[t] = tsum;
    __syncthreads();
    for (int off = 1; off < 256; off <<= 1) {
        int u = (t >= off) ? s[t - off] : 0;
        __syncthreads();
        s[t] += u;
        __syncthreads();
    }
    int excl = s[t] - tsum;
    if (base + 0 < n) row_ptr[base + 0] = excl;
    if (base + 1 < n) row_ptr[base + 1] = excl + v0;
    if (base + 2 < n) row_ptr[base + 2] = excl + v0 + v1;
    if (base + 3 < n) row_ptr[base + 3] = excl + v0 + v1 + v2;
    if (t == 255) blockSums[blockIdx.x] = s[255];
}

// scanC with inlined block-sum scan (B <= 64 blocks): wave 0 scans blockSums, no scanB launch
__global__ __launch_bounds__(256) void scanC(int* __restrict__ row_ptr,
                                             const int* __restrict__ blockSums,
                                             int n, int E, int B) {
    __shared__ int soff;
    int t = threadIdx.x;
    if (t < 64) {
        int v = (t < B) ? blockSums[t] : 0;
        int orig = v;
        for (int off = 1; off < 64; off <<= 1) {
            int u = __shfl_up(v, off, 64);
            if (t >= off) v += u;
        }
        if (t == (int)blockIdx.x) soff = v - orig;  // exclusive offset of this block
    }
    __syncthreads();
    int off = soff;
    int base = blockIdx.x * 1024 + t * 4;
    #pragma unroll
    for (int j = 0; j < 4; ++j)
        if (base + j < n) row_ptr[base + j] += off;
    if (blockIdx.x == 0 && t == 0) row_ptr[n] = E;
}

// atomic-free CSR fill: slot = row_ptr[d] + rank[e]
__global__ void fill_nr(const int* __restrict__ src, const int* __restrict__ dst,
                        const unsigned short* __restrict__ rank, int E,
                        const int* __restrict__ row_ptr, const float* __restrict__ dis,
                        unsigned int* __restrict__ edges) {
    int e = blockIdx.x * blockDim.x + threadIdx.x;
    if (e >= E) return;
    int d = dst[e], s = src[e];
    int slot = row_ptr[d] + (int)rank[e];
    float coef = dis[s] * dis[d];
    edges[slot] = (unsigned)s |
                  ((unsigned)__half_as_ushort(__float2half_rn(coef)) << 16);
}

__device__ __forceinline__ void unpack_edge(unsigned int w, int& s, float& c) {
    s = (int)(w & 0xffffu);
    c = __half2float(__ushort_as_half((unsigned short)(w >> 16)));
}

// ---------------- MFMA GEMM: Y[M,N](fp16) = X[M,128] @ Wt[N][128](fp16) ----------------
// F32IN: layer-1 reads f32 x directly, converts in-register (no cvt_x pass).

template <int N, bool F32IN>
__global__ __launch_bounds__(256) void gemm_mfma(const void* __restrict__ Xin,
                                                 const _Float16* __restrict__ Wt,
                                                 _Float16* __restrict__ Y, int M) {
    constexpr int NT = N / 16;
    int wave = threadIdx.x >> 6;
    int lane = threadIdx.x & 63;
    int m0 = blockIdx.x * 64 + wave * 16;
    int r = lane & 15;
    int kb = lane >> 4;
    int ar = m0 + r; if (ar >= M) ar = M - 1;  // clamp (A row m only affects D row m)
    f32x4 acc[NT] = {};
    #pragma unroll
    for (int kk = 0; kk < 128; kk += 32) {
        half8v a;
        if constexpr (F32IN) {
            const float* arow = (const float*)Xin + (size_t)ar * 128 + kb * 8 + kk;
            float4 f0 = *(const float4*)arow;
            float4 f1 = *(const float4*)(arow + 4);
            a = (half8v){(_Float16)f0.x, (_Float16)f0.y, (_Float16)f0.z, (_Float16)f0.w,
                         (_Float16)f1.x, (_Float16)f1.y, (_Float16)f1.z, (_Float16)f1.w};
        } else {
            a = *(const half8v*)((const _Float16*)Xin + (size_t)ar * 128 + kb * 8 + kk);
        }
        #pragma unroll
        for (int c = 0; c < NT; ++c) {
            half8v b = *(const half8v*)(Wt + (size_t)(c * 16 + r) * 128 + kk + kb * 8);
            acc[c] = __builtin_amdgcn_mfma_f32_16x16x32_f16(a, b, acc[c], 0, 0, 0);
        }
    }
    #pragma unroll
    for (int j = 0; j < 4; ++j) {
        int row = m0 + kb * 4 + j;
        if (row < M) {
            #pragma unroll
            for (int c = 0; c < NT; ++c)
                Y[(size_t)row * N + c * 16 + r] = (_Float16)acc[c][j];
        }
    }
}

// ---------------- aggregation D=128: wave per node, lane = half2(2 dims), fp16 in/out ----------------

__global__ __launch_bounds__(256) void agg_gcn128(const __half2* __restrict__ hp,
                                                  const int* __restrict__ row_ptr,
                                                  const unsigned int* __restrict__ edges,
                                                  const float* __restrict__ dis,
                                                  const float* __restrict__ bias,
                                                  __half2* __restrict__ out, int n) {
    int wid = (blockIdx.x * 256 + threadIdx.x) >> 6;
    if (wid >= n) return;
    int lane = threadIdx.x & 63;
    int beg = row_ptr[wid], end = row_ptr[wid + 1];
    float di = dis[wid];
    float cs = di * di;
    float2 sv = __half22float2(hp[(size_t)wid * 64 + lane]);
    float2 a0 = {cs * sv.x, cs * sv.y};
    float2 a1 = {0.f, 0.f}, a2 = {0.f, 0.f}, a3 = {0.f, 0.f};
    int e = beg;
    for (; e + 4 <= end; e += 4) {
        unsigned int w0 = edges[e], w1 = edges[e + 1], w2 = edges[e + 2], w3 = edges[e + 3];
        int s0, s1, s2, s3; float c0, c1, c2, c3;
        unpack_edge(w0, s0, c0); unpack_edge(w1, s1, c1);
        unpack_edge(w2, s2, c2); unpack_edge(w3, s3, c3);
        float2 u0 = __half22float2(hp[(size_t)s0 * 64 + lane]);
        float2 u1 = __half22float2(hp[(size_t)s1 * 64 + lane]);
        float2 u2 = __half22float2(hp[(size_t)s2 * 64 + lane]);
        float2 u3 = __half22float2(hp[(size_t)s3 * 64 + lane]);
        a0.x += c0 * u0.x; a0.y += c0 * u0.y;
        a1.x += c1 * u1.x; a1.y += c1 * u1.y;
        a2.x += c2 * u2.x; a2.y += c2 * u2.y;
        a3.x += c3 * u3.x; a3.y += c3 * u3.y;
    }
    for (; e < end; ++e) {
        int s0; float c0;
        unpack_edge(edges[e], s0, c0);
        float2 u0 = __half22float2(hp[(size_t)s0 * 64 + lane]);
        a0.x += c0 * u0.x; a0.y += c0 * u0.y;
    }
    float2 bv = ((const float2*)bias)[lane];
    float ox = fmaxf(a0.x + a1.x + a2.x + a3.x + bv.x, 0.f);
    float oy = fmaxf(a0.y + a1.y + a2.y + a3.y + bv.y, 0.f);
    out[(size_t)wid * 64 + lane] = __floats2half2_rn(ox, oy);
}

// ---------------- aggregation D=64: 2 nodes per wave (32 lanes x half2), fp16 in/out ----------------

__global__ __launch_bounds__(256) void agg_gcn64(const __half2* __restrict__ hp,
                                                 const int* __restrict__ row_ptr,
                                                 const unsigned int* __restrict__ edges,
                                                 const float* __restrict__ dis,
                                                 const float* __restrict__ bias,
                                                 __half2* __restrict__ out, int n) {
    int node = (blockIdx.x * 256 + threadIdx.x) >> 5;
    if (node >= n) return;
    int l = threadIdx.x & 31;
    int beg = row_ptr[node], end = row_ptr[node + 1];
    float di = dis[node];
    float cs = di * di;
    float2 sv = __half22float2(hp[(size_t)node * 32 + l]);
    float2 a0 = {cs * sv.x, cs * sv.y};
    float2 a1 = {0.f, 0.f};
    int e = beg;
    for (; e + 2 <= end; e += 2) {
        unsigned int w0 = edges[e], w1 = edges[e + 1];
        int s0, s1; float c0, c1;
        unpack_edge(w0, s0, c0); unpack_edge(w1, s1, c1);
        float2 u0 = __half22float2(hp[(size_t)s0 * 32 + l]);
        float2 u1 = __half22float2(hp[(size_t)s1 * 32 + l]);
        a0.x += c0 * u0.x; a0.y += c0 * u0.y;
        a1.x += c1 * u1.x; a1.y += c1 * u1.y;
    }
    if (e < end) {
        int s0; float c0;
        unpack_edge(edges[e], s0, c0);
        float2 u0 = __half22float2(hp[(size_t)s0 * 32 + l]);
        a0.x += c0 * u0.x; a0.y += c0 * u0.y;
    }
    float2 bv = ((const float2*)bias)[l];
    float ox = fmaxf(a0.x + a1.x + bv.x, 0.f);
    float oy = fmaxf(a0.y + a1.y + bv.y, 0.f);
    out[(size_t)node * 32 + l] = __floats2half2_rn(ox, oy);
}

// ---------------- projection + relu + row-normalize (fp16 input, f32 output) ----------------

__global__ __launch_bounds__(256) void proj_norm2(const _Float16* __restrict__ O,
                                                  const float* __restrict__ Wp,
                                                  float* __restrict__ P, int n) {
    __shared__ float oT[64 * 68];  // [k][node], stride 68 keeps float4 16B-aligned
    __shared__ float Ws[64 * 64];  // [k][col]
    int t = threadIdx.x;
    int base = blockIdx.x * 64;
    for (int j = t * 4; j < 4096; j += 1024)
        *(float4*)&Ws[j] = *(const float4*)&Wp[j];
    for (int j = t * 4; j < 4096; j += 1024) {
        int row = j >> 6;   // node-in-block
        int col = j & 63;   // k
        int node = base + row;
        half4v hv = (node < n) ? *(const half4v*)&O[(size_t)node * 64 + col]
                               : (half4v){(_Float16)0, (_Float16)0, (_Float16)0, (_Float16)0};
        oT[(col + 0) * 68 + row] = (float)hv[0];
        oT[(col + 1) * 68 + row] = (float)hv[1];
        oT[(col + 2) * 68 + row] = (float)hv[2];
        oT[(col + 3) * 68 + row] = (float)hv[3];
    }
    __syncthreads();
    int cg = t & 15;   // col group (4 cols)
    int ng = t >> 4;   // node group (4 nodes)
    float acc[4][4] = {};
    const float* otp = &oT[ng * 4];
    const float* wsp = &Ws[cg * 4];
    #pragma unroll 2
    for (int k = 0; k < 64; ++k) {
        float4 ov = *(const float4*)&otp[k * 68];
        float4 wv = *(const float4*)&wsp[k * 64];
        #pragma unroll
        for (int i = 0; i < 4; ++i) {
            float o = (&ov.x)[i];
            acc[i][0] += o * wv.x;
            acc[i][1] += o * wv.y;
            acc[i][2] += o * wv.z;
            acc[i][3] += o * wv.w;
        }
    }
    #pragma unroll
    for (int i = 0; i < 4; ++i) {
        float4 p;
        p.x = fmaxf(acc[i][0], 0.f);
        p.y = fmaxf(acc[i][1], 0.f);
        p.z = fmaxf(acc[i][2], 0.f);
        p.w = fmaxf(acc[i][3], 0.f);
        float ss = p.x * p.x + p.y * p.y + p.z * p.z + p.w * p.w;
        #pragma unroll
        for (int off = 1; off < 16; off <<= 1) ss += __shfl_xor(ss, off, 64);
        float norm = sqrtf(ss);
        float sc = 1.0f / fmaxf(norm, 1e-12f);
        int node = base + ng * 4 + i;
        if (node < n) {
            p.x *= sc; p.y *= sc; p.z *= sc; p.w *= sc;
            *(float4*)&P[(size_t)node * 64 + cg * 4] = p;
        }
    }
}

// ---------------- launch ----------------

static inline size_t ws_align(size_t x) { return (x + 255) & ~(size_t)255; }

extern "C" void kernel_launch(void* const* d_in, const int* in_sizes, int n_in,
                              void* d_out, int out_size, void* d_ws, size_t ws_size,
                              hipStream_t stream) {
    const float* x  = (const float*)d_in[0];
    const int*   ei = (const int*)d_in[1];
    const float* W1 = (const float*)d_in[2];
    const float* b1 = (const float*)d_in[3];
    const float* W2 = (const float*)d_in[4];
    const float* b2 = (const float*)d_in[5];
    const float* W3 = (const float*)d_in[6];
    const float* b3 = (const float*)d_in[7];
    const float* Wp = (const float*)d_in[8];

    int n = in_sizes[0] / 128;
    int E = in_sizes[1] / 2;
    const int* src = ei;
    const int* dst = ei + E;

    char* ws = (char*)d_ws;
    size_t off = 0;
    auto alloc = [&](size_t bytes) -> void* {
        void* p = ws + off;
        off = ws_align(off + bytes);
        return p;
    };
    _Float16* bufA = (_Float16*)alloc((size_t)n * 128 * 2);  // gemm out / agg in
    _Float16* bufB = (_Float16*)alloc((size_t)n * 128 * 2);  // agg out / gemm in
    _Float16* Wt1  = (_Float16*)alloc(128 * 128 * 2);
    _Float16* Wt2  = (_Float16*)alloc(128 * 128 * 2);
    _Float16* Wt3  = (_Float16*)alloc(64 * 128 * 2);
    int*   cnt      = (int*)alloc((size_t)n * 4);
    float* dis      = (float*)alloc((size_t)n * 4);
    int*   row_ptr  = (int*)alloc((size_t)(n + 1) * 4);
    unsigned short* rank = (unsigned short*)alloc((size_t)E * 2);
    unsigned int* edges = (unsigned int*)alloc((size_t)E * 4);
    int*   blockSums = (int*)alloc(256);
    (void)off; (void)ws_size;

    int B = (n + 1023) / 1024;
    int wz = 40960 + n;
    cvt_wz<<<(wz + 255) / 256, 256, 0, stream>>>(W1, W2, W3, Wt1, Wt2, Wt3, cnt, n);
    count_rank<<<(E + 255) / 256, 256, 0, stream>>>(dst, E, cnt, rank);
    scanA<<<B, 256, 0, stream>>>(cnt, row_ptr, blockSums, dis, n);
    scanC<<<B, 256, 0, stream>>>(row_ptr, blockSums, n, E, B);
    fill_nr<<<(E + 255) / 256, 256, 0, stream>>>(src, dst, rank, E, row_ptr, dis, edges);

    int gblocks = (n + 63) / 64;
    int ablocks = (n + 3) / 4;
    int a64blocks = (n + 7) / 8;
    int pblocks = (n + 63) / 64;
    float* outp = (float*)d_out;

    gemm_mfma<128, true><<<gblocks, 256, 0, stream>>>(x, Wt1, bufA, n);
    agg_gcn128<<<ablocks, 256, 0, stream>>>((const __half2*)bufA, row_ptr, edges, dis, b1,
                                            (__half2*)bufB, n);
    gemm_mfma<128, false><<<gblocks, 256, 0, stream>>>(bufB, Wt2, bufA, n);
    agg_gcn128<<<ablocks, 256, 0, stream>>>((const __half2*)bufA, row_ptr, edges, dis, b2,
                                            (__half2*)bufB, n);
    gemm_mfma<64, false><<<gblocks, 256, 0, stream>>>(bufB, Wt3, bufA, n);
    agg_gcn64<<<a64blocks, 256, 0, stream>>>((const __half2*)bufA, row_ptr, edges, dis, b3,
                                             (__half2*)bufB, n);
    proj_norm2<<<pblocks, 256, 0, stream>>>(bufB, Wp, outp, n);
}

// Round 11
// 230.264 us; speedup vs baseline: 1.5421x; 1.0756x over previous
//
#include <hip/hip_runtime.h>
#include <hip/hip_fp16.h>

typedef _Float16 half8v __attribute__((ext_vector_type(8)));
typedef _Float16 half4v __attribute__((ext_vector_type(4)));
typedef _Float16 half2v __attribute__((ext_vector_type(2)));
typedef float f32x4 __attribute__((ext_vector_type(4)));

// ---------------- fused: transpose-convert W1/W2/W3 to fp16 Wt[N][128] + zero cnt ----------------

__global__ void cvt_wz(const float* __restrict__ W1, const float* __restrict__ W2,
                       const float* __restrict__ W3,
                       _Float16* __restrict__ Wt1, _Float16* __restrict__ Wt2,
                       _Float16* __restrict__ Wt3,
                       int* __restrict__ cnt, int n) {
    int i = blockIdx.x * blockDim.x + threadIdx.x;
    if (i < 16384) {
        int nn = i >> 7, kk = i & 127;
        Wt1[i] = (_Float16)W1[kk * 128 + nn];
    } else if (i < 32768) {
        int j = i - 16384; int nn = j >> 7, kk = j & 127;
        Wt2[j] = (_Float16)W2[kk * 128 + nn];
    } else if (i < 40960) {
        int j = i - 32768; int nn = j >> 7, kk = j & 127;
        Wt3[j] = (_Float16)W3[kk * 64 + nn];
    }
    int z = i - 40960;
    if (z >= 0 && z < n) cnt[z] = 0;
}

// ---------------- degree count; atomic's return value IS the edge's rank in its row ----------------

__global__ void count_rank(const int* __restrict__ dst, int E, int* __restrict__ cnt,
                           unsigned short* __restrict__ rank) {
    int e = blockIdx.x * blockDim.x + threadIdx.x;
    if (e < E) rank[e] = (unsigned short)atomicAdd(&cnt[dst[e]], 1);
}

// scanA: block-local exclusive scan of cnt (1024 elems/block) + dis = rsqrt(deg+1)
__global__ __launch_bounds__(256) void scanA(const int* __restrict__ cnt,
                                             int* __restrict__ row_ptr,
                                             int* __restrict__ blockSums,
                                             float* __restrict__ dis, int n) {
    __shared__ int s[256];
    int t = threadIdx.x;
    int base = blockIdx.x * 1024 + t * 4;
    int v0 = (base + 0 < n) ? cnt[base + 0] : 0;
    int v1 = (base + 1 < n) ? cnt[base + 1] : 0;
    int v2 = (base + 2 < n) ? cnt[base + 2] : 0;
    int v3 = (base + 3 < n) ? cnt[base + 3] : 0;
    if (base + 0 < n) dis[base + 0] = rsqrtf((float)(v0 + 1));
    if (base + 1 < n) dis[base + 1] = rsqrtf((float)(v1 + 1));
    if (base + 2 < n) dis[base + 2] = rsqrtf((float)(v2 + 1));
    if (base + 3 < n) dis[base + 3] = rsqrtf((float)(v3 + 1));
    int tsum = v0 + v1 + v2 + v3;
    s[t] = tsum;
    __syncthreads();
    for (int off = 1; off < 256; off <<= 1) {
        int u = (t >= off) ? s[t - off] : 0;
        __syncthreads();
        s[t] += u;
        __syncthreads();
    }
    int excl = s[t] - tsum;
    if (base + 0 < n) row_ptr[base + 0] = excl;
    if (base + 1 < n) row_ptr[base + 1] = excl + v0;
    if (base + 2 < n) row_ptr[base + 2] = excl + v0 + v1;
    if (base + 3 < n) row_ptr[base + 3] = excl + v0 + v1 + v2;
    if (t == 255) blockSums[blockIdx.x] = s[255];
}

// scanC with inlined block-sum scan (B <= 64 blocks)
__global__ __launch_bounds__(256) void scanC(int* __restrict__ row_ptr,
                                             const int* __restrict__ blockSums,
                                             int n, int E, int B) {
    __shared__ int soff;
    int t = threadIdx.x;
    if (t < 64) {
        int v = (t < B) ? blockSums[t] : 0;
        int orig = v;
        for (int off = 1; off < 64; off <<= 1) {
            int u = __shfl_up(v, off, 64);
            if (t >= off) v += u;
        }
        if (t == (int)blockIdx.x) soff = v - orig;
    }
    __syncthreads();
    int off = soff;
    int base = blockIdx.x * 1024 + t * 4;
    #pragma unroll
    for (int j = 0; j < 4; ++j)
        if (base + j < n) row_ptr[base + j] += off;
    if (blockIdx.x == 0 && t == 0) row_ptr[n] = E;
}

// atomic-free CSR fill: slot = row_ptr[d] + rank[e]
__global__ void fill_nr(const int* __restrict__ src, const int* __restrict__ dst,
                        const unsigned short* __restrict__ rank, int E,
                        const int* __restrict__ row_ptr, const float* __restrict__ dis,
                        unsigned int* __restrict__ edges) {
    int e = blockIdx.x * blockDim.x + threadIdx.x;
    if (e >= E) return;
    int d = dst[e], s = src[e];
    int slot = row_ptr[d] + (int)rank[e];
    float coef = dis[s] * dis[d];
    edges[slot] = (unsigned)s |
                  ((unsigned)__half_as_ushort(__float2half_rn(coef)) << 16);
}

__device__ __forceinline__ void unpack_edge(unsigned int w, int& s, float& c) {
    s = (int)(w & 0xffffu);
    c = __half2float(__ushort_as_half((unsigned short)(w >> 16)));
}

// ---------------- MFMA GEMM layer 1: Y[M,128](fp16) = f32 x @ Wt1[128][128] ----------------

template <int N, bool F32IN>
__global__ __launch_bounds__(256) void gemm_mfma(const void* __restrict__ Xin,
                                                 const _Float16* __restrict__ Wt,
                                                 _Float16* __restrict__ Y, int M) {
    constexpr int NT = N / 16;
    int wave = threadIdx.x >> 6;
    int lane = threadIdx.x & 63;
    int m0 = blockIdx.x * 64 + wave * 16;
    int r = lane & 15;
    int kb = lane >> 4;
    int ar = m0 + r; if (ar >= M) ar = M - 1;
    f32x4 acc[NT] = {};
    #pragma unroll
    for (int kk = 0; kk < 128; kk += 32) {
        half8v a;
        if constexpr (F32IN) {
            const float* arow = (const float*)Xin + (size_t)ar * 128 + kb * 8 + kk;
            float4 f0 = *(const float4*)arow;
            float4 f1 = *(const float4*)(arow + 4);
            a = (half8v){(_Float16)f0.x, (_Float16)f0.y, (_Float16)f0.z, (_Float16)f0.w,
                         (_Float16)f1.x, (_Float16)f1.y, (_Float16)f1.z, (_Float16)f1.w};
        } else {
            a = *(const half8v*)((const _Float16*)Xin + (size_t)ar * 128 + kb * 8 + kk);
        }
        #pragma unroll
        for (int c = 0; c < NT; ++c) {
            half8v b = *(const half8v*)(Wt + (size_t)(c * 16 + r) * 128 + kk + kb * 8);
            acc[c] = __builtin_amdgcn_mfma_f32_16x16x32_f16(a, b, acc[c], 0, 0, 0);
        }
    }
    #pragma unroll
    for (int j = 0; j < 4; ++j) {
        int row = m0 + kb * 4 + j;
        if (row < M) {
            #pragma unroll
            for (int c = 0; c < NT; ++c)
                Y[(size_t)row * N + c * 16 + r] = (_Float16)acc[c][j];
        }
    }
}

// ---------------- FUSED agg(D=128) + GEMM: out = relu(agg(h)+b) @ Wt[NOUT][128] ----------------
// block = 16 nodes, 4 waves. Agg: wave per node (4 sequential), lane = half2 of 2 dims.
// Aggregated rows -> LDS A[16][136] fp16 (pad-> 272B rows, 16B aligned). Then one
// 16x128 @ 128xNOUT MFMA tile: wave w covers col-tiles w*NOUT/64 .. (NT = NOUT/64).

template <int NOUT>
__global__ __launch_bounds__(256) void agg_gemm(const __half2* __restrict__ hp,
                                                const int* __restrict__ row_ptr,
                                                const unsigned int* __restrict__ edges,
                                                const float* __restrict__ dis,
                                                const float* __restrict__ bias,
                                                const _Float16* __restrict__ Wt,
                                                _Float16* __restrict__ Y, int n) {
    __shared__ _Float16 As[16][136];
    int t = threadIdx.x;
    int wave = t >> 6;
    int lane = t & 63;
    int m0 = blockIdx.x * 16;
    #pragma unroll
    for (int i = 0; i < 4; ++i) {
        int node = m0 + wave * 4 + i;
        float ox = 0.f, oy = 0.f;
        if (node < n) {
            int beg = row_ptr[node], end = row_ptr[node + 1];
            float di = dis[node];
            float cs = di * di;
            float2 sv = __half22float2(hp[(size_t)node * 64 + lane]);
            float2 a0 = {cs * sv.x, cs * sv.y};
            float2 a1 = {0.f, 0.f}, a2 = {0.f, 0.f}, a3 = {0.f, 0.f};
            int e = beg;
            for (; e + 4 <= end; e += 4) {
                unsigned int w0 = edges[e], w1 = edges[e + 1], w2 = edges[e + 2], w3 = edges[e + 3];
                int s0, s1, s2, s3; float c0, c1, c2, c3;
                unpack_edge(w0, s0, c0); unpack_edge(w1, s1, c1);
                unpack_edge(w2, s2, c2); unpack_edge(w3, s3, c3);
                float2 u0 = __half22float2(hp[(size_t)s0 * 64 + lane]);
                float2 u1 = __half22float2(hp[(size_t)s1 * 64 + lane]);
                float2 u2 = __half22float2(hp[(size_t)s2 * 64 + lane]);
                float2 u3 = __half22float2(hp[(size_t)s3 * 64 + lane]);
                a0.x += c0 * u0.x; a0.y += c0 * u0.y;
                a1.x += c1 * u1.x; a1.y += c1 * u1.y;
                a2.x += c2 * u2.x; a2.y += c2 * u2.y;
                a3.x += c3 * u3.x; a3.y += c3 * u3.y;
            }
            for (; e < end; ++e) {
                int s0; float c0;
                unpack_edge(edges[e], s0, c0);
                float2 u0 = __half22float2(hp[(size_t)s0 * 64 + lane]);
                a0.x += c0 * u0.x; a0.y += c0 * u0.y;
            }
            float2 bv = ((const float2*)bias)[lane];
            ox = fmaxf(a0.x + a1.x + a2.x + a3.x + bv.x, 0.f);
            oy = fmaxf(a0.y + a1.y + a2.y + a3.y + bv.y, 0.f);
        }
        *(half2v*)&As[wave * 4 + i][2 * lane] = (half2v){(_Float16)ox, (_Float16)oy};
    }
    __syncthreads();
    constexpr int NT = NOUT / 64;  // col tiles per wave
    int r = lane & 15;
    int kb = lane >> 4;
    f32x4 acc[NT] = {};
    #pragma unroll
    for (int kk = 0; kk < 128; kk += 32) {
        half8v a = *(const half8v*)&As[r][kb * 8 + kk];
        #pragma unroll
        for (int c = 0; c < NT; ++c) {
            int ct = wave * NT + c;
            half8v b = *(const half8v*)(Wt + (size_t)(ct * 16 + r) * 128 + kk + kb * 8);
            acc[c] = __builtin_amdgcn_mfma_f32_16x16x32_f16(a, b, acc[c], 0, 0, 0);
        }
    }
    #pragma unroll
    for (int j = 0; j < 4; ++j) {
        int row = m0 + kb * 4 + j;
        if (row < n) {
            #pragma unroll
            for (int c = 0; c < NT; ++c)
                Y[(size_t)row * NOUT + (wave * NT + c) * 16 + r] = (_Float16)acc[c][j];
        }
    }
}

// ---------------- FUSED agg(D=64) + projection + relu + row-normalize ----------------
// block = 64 nodes. Agg staging: 4 passes x 16 nodes; 16 threads/node, 4 dims each,
// written straight into the transposed oT[k][node] proj layout. Then proj as before.

__global__ __launch_bounds__(256) void agg_proj(const _Float16* __restrict__ h,
                                                const int* __restrict__ row_ptr,
                                                const unsigned int* __restrict__ edges,
                                                const float* __restrict__ dis,
                                                const float* __restrict__ b3,
                                                const float* __restrict__ Wp,
                                                float* __restrict__ P, int n) {
    __shared__ float oT[64 * 68];
    __shared__ float Ws[64 * 64];
    int t = threadIdx.x;
    int base = blockIdx.x * 64;
    for (int j = t * 4; j < 4096; j += 1024)
        *(float4*)&Ws[j] = *(const float4*)&Wp[j];
    int cg = t & 15;   // col group: dims 4*cg..+3
    int ng = t >> 4;   // node-in-pass 0..15
    int c0 = cg * 4;
    float4 bv = *(const float4*)&b3[c0];
    #pragma unroll
    for (int pass = 0; pass < 4; ++pass) {
        int ni = pass * 16 + ng;
        int node = base + ni;
        float ax = 0.f, ay = 0.f, az = 0.f, aw = 0.f;
        if (node < n) {
            int beg = row_ptr[node], end = row_ptr[node + 1];
            float di = dis[node];
            float cs = di * di;
            half4v sv = *(const half4v*)&h[(size_t)node * 64 + c0];
            ax = cs * (float)sv[0]; ay = cs * (float)sv[1];
            az = cs * (float)sv[2]; aw = cs * (float)sv[3];
            float bx = 0.f, by = 0.f, bz = 0.f, bw = 0.f;
            int e = beg;
            for (; e + 2 <= end; e += 2) {
                unsigned int w0 = edges[e], w1 = edges[e + 1];
                int s0, s1; float cc0, cc1;
                unpack_edge(w0, s0, cc0); unpack_edge(w1, s1, cc1);
                half4v u0 = *(const half4v*)&h[(size_t)s0 * 64 + c0];
                half4v u1 = *(const half4v*)&h[(size_t)s1 * 64 + c0];
                ax += cc0 * (float)u0[0]; ay += cc0 * (float)u0[1];
                az += cc0 * (float)u0[2]; aw += cc0 * (float)u0[3];
                bx += cc1 * (float)u1[0]; by += cc1 * (float)u1[1];
                bz += cc1 * (float)u1[2]; bw += cc1 * (float)u1[3];
            }
            if (e < end) {
                int s0; float cc0;
                unpack_edge(edges[e], s0, cc0);
                half4v u0 = *(const half4v*)&h[(size_t)s0 * 64 + c0];
                ax += cc0 * (float)u0[0]; ay += cc0 * (float)u0[1];
                az += cc0 * (float)u0[2]; aw += cc0 * (float)u0[3];
            }
            ax = fmaxf(ax + bx + bv.x, 0.f);
            ay = fmaxf(ay + by + bv.y, 0.f);
            az = fmaxf(az + bz + bv.z, 0.f);
            aw = fmaxf(aw + bw + bv.w, 0.f);
        }
        oT[(c0 + 0) * 68 + ni] = ax;
        oT[(c0 + 1) * 68 + ni] = ay;
        oT[(c0 + 2) * 68 + ni] = az;
        oT[(c0 + 3) * 68 + ni] = aw;
    }
    __syncthreads();
    float acc[4][4] = {};
    const float* otp = &oT[ng * 4];
    const float* wsp = &Ws[cg * 4];
    #pragma unroll 2
    for (int k = 0; k < 64; ++k) {
        float4 ov = *(const float4*)&otp[k * 68];
        float4 wv = *(const float4*)&wsp[k * 64];
        #pragma unroll
        for (int i = 0; i < 4; ++i) {
            float o = (&ov.x)[i];
            acc[i][0] += o * wv.x;
            acc[i][1] += o * wv.y;
            acc[i][2] += o * wv.z;
            acc[i][3] += o * wv.w;
        }
    }
    #pragma unroll
    for (int i = 0; i < 4; ++i) {
        float4 p;
        p.x = fmaxf(acc[i][0], 0.f);
        p.y = fmaxf(acc[i][1], 0.f);
        p.z = fmaxf(acc[i][2], 0.f);
        p.w = fmaxf(acc[i][3], 0.f);
        float ss = p.x * p.x + p.y * p.y + p.z * p.z + p.w * p.w;
        #pragma unroll
        for (int off = 1; off < 16; off <<= 1) ss += __shfl_xor(ss, off, 64);
        float norm = sqrtf(ss);
        float sc = 1.0f / fmaxf(norm, 1e-12f);
        int node = base + ng * 4 + i;
        if (node < n) {
            p.x *= sc; p.y *= sc; p.z *= sc; p.w *= sc;
            *(float4*)&P[(size_t)node * 64 + cg * 4] = p;
        }
    }
}

// ---------------- launch ----------------

static inline size_t ws_align(size_t x) { return (x + 255) & ~(size_t)255; }

extern "C" void kernel_launch(void* const* d_in, const int* in_sizes, int n_in,
                              void* d_out, int out_size, void* d_ws, size_t ws_size,
                              hipStream_t stream) {
    const float* x  = (const float*)d_in[0];
    const int*   ei = (const int*)d_in[1];
    const float* W1 = (const float*)d_in[2];
    const float* b1 = (const float*)d_in[3];
    const float* W2 = (const float*)d_in[4];
    const float* b2 = (const float*)d_in[5];
    const float* W3 = (const float*)d_in[6];
    const float* b3 = (const float*)d_in[7];
    const float* Wp = (const float*)d_in[8];

    int n = in_sizes[0] / 128;
    int E = in_sizes[1] / 2;
    const int* src = ei;
    const int* dst = ei + E;

    char* ws = (char*)d_ws;
    size_t off = 0;
    auto alloc = [&](size_t bytes) -> void* {
        void* p = ws + off;
        off = ws_align(off + bytes);
        return p;
    };
    _Float16* bufA = (_Float16*)alloc((size_t)n * 128 * 2);
    _Float16* bufB = (_Float16*)alloc((size_t)n * 128 * 2);
    _Float16* Wt1  = (_Float16*)alloc(128 * 128 * 2);
    _Float16* Wt2  = (_Float16*)alloc(128 * 128 * 2);
    _Float16* Wt3  = (_Float16*)alloc(64 * 128 * 2);
    int*   cnt      = (int*)alloc((size_t)n * 4);
    float* dis      = (float*)alloc((size_t)n * 4);
    int*   row_ptr  = (int*)alloc((size_t)(n + 1) * 4);
    unsigned short* rank = (unsigned short*)alloc((size_t)E * 2);
    unsigned int* edges = (unsigned int*)alloc((size_t)E * 4);
    int*   blockSums = (int*)alloc(256);
    (void)off; (void)ws_size;

    int B = (n + 1023) / 1024;
    int wz = 40960 + n;
    cvt_wz<<<(wz + 255) / 256, 256, 0, stream>>>(W1, W2, W3, Wt1, Wt2, Wt3, cnt, n);
    count_rank<<<(E + 255) / 256, 256, 0, stream>>>(dst, E, cnt, rank);
    scanA<<<B, 256, 0, stream>>>(cnt, row_ptr, blockSums, dis, n);
    scanC<<<B, 256, 0, stream>>>(row_ptr, blockSums, n, E, B);
    fill_nr<<<(E + 255) / 256, 256, 0, stream>>>(src, dst, rank, E, row_ptr, dis, edges);

    int gblocks = (n + 63) / 64;
    int fblocks = (n + 15) / 16;
    int pblocks = (n + 63) / 64;
    float* outp = (float*)d_out;

    gemm_mfma<128, true><<<gblocks, 256, 0, stream>>>(x, Wt1, bufA, n);
    agg_gemm<128><<<fblocks, 256, 0, stream>>>((const __half2*)bufA, row_ptr, edges, dis, b1,
                                               Wt2, bufB, n);
    agg_gemm<64><<<fblocks, 256, 0, stream>>>((const __half2*)bufB, row_ptr, edges, dis, b2,
                                              Wt3, bufA, n);
    agg_proj<<<pblocks, 256, 0, stream>>>(bufA, row_ptr, edges, dis, b3, Wp, outp, n);
}